// Round 1
// baseline (4561.518 us; speedup 1.0000x reference)
//
#include <hip/hip_runtime.h>

typedef __attribute__((ext_vector_type(8))) short bf16x8;
typedef __attribute__((ext_vector_type(4))) float floatx4;
typedef __attribute__((ext_vector_type(4))) unsigned int uintx4;

#define EPSF 1e-5f
#define RS512 0.04419417382415922f /* 1/sqrt(512) */

__device__ __forceinline__ unsigned short f2bf(float f) {
  unsigned int u = __float_as_uint(f);
  u += 0x7fffu + ((u >> 16) & 1u);
  return (unsigned short)(u >> 16);
}

union BFrag { bf16x8 v; int i[4]; unsigned short s[8]; };

// ---------------- Kernel 1: fused qkv conv + BN + PReLU, bf16 emit ----------
// Q: [8][4000][512] token-major; K: [8][4096][512] token-major (pre-scaled by
// 1/sqrt(512), rows >=4000 zeroed); V: [8][512][4096] d-major (cols>=4000 zero)
__global__ __launch_bounds__(256) void qkv_kernel(
    const float* __restrict__ x,
    const float* __restrict__ Wq, const float* __restrict__ bq,
    const float* __restrict__ gq, const float* __restrict__ beq,
    const float* __restrict__ mq, const float* __restrict__ vq,
    const float* __restrict__ aq,
    unsigned short* __restrict__ Q, unsigned short* __restrict__ K,
    unsigned short* __restrict__ V) {
  const int b = blockIdx.y;
  const int t0 = blockIdx.x << 4;
  const int tid = threadIdx.x;

  if (t0 >= 4000) {
    // zero-pad K rows and V columns for t in [4000,4096)
    unsigned int* Kp = (unsigned int*)(K + (size_t)(b * 4096 + t0) * 512);
    for (int i = tid; i < 4096; i += 256) Kp[i] = 0u;
    for (int i = tid; i < 4096; i += 256) {
      int d = i >> 3, u = i & 7;
      ((unsigned int*)(V + (size_t)(b * 512 + d) * 4096 + t0))[u] = 0u;
    }
    return;
  }

  __shared__ unsigned short xs[16 * 1024];  // [lt][i*32+f] bf16  (32 KB)
  __shared__ float sW[1536];                // folded qkv weights
  __shared__ float sB[48];                  // folded qkv biases
  __shared__ unsigned short vsm[512 * 18];  // V transpose staging (18 KB)

  // fold BN into conv weights/bias (K additionally scaled by 1/sqrt(512))
  for (int idx = tid; idx < 1536; idx += 256) {
    int n = idx >> 9, ch = (idx >> 5) & 15;
    float inv = gq[n * 16 + ch] * rsqrtf(vq[n * 16 + ch] + EPSF);
    if (n == 1) inv *= RS512;
    sW[idx] = Wq[idx] * inv;
  }
  if (tid < 48) {
    int n = tid >> 4;
    float inv = gq[tid] * rsqrtf(vq[tid] + EPSF);
    float bb = (bq[tid] - mq[tid]) * inv + beq[tid];
    if (n == 1) bb *= RS512;
    sB[tid] = bb;
  }
  {  // stage x[b,:,:,t0..t0+15] into LDS, t-major, bf16
    int lt = tid & 15, rg = tid >> 4;
    const float* xb = x + (size_t)b * 1024 * 4000 + t0 + lt;
    for (int rr = rg; rr < 1024; rr += 16)
      xs[lt * 1024 + rr] = f2bf(xb[(size_t)rr * 4000]);
  }
  __syncthreads();

  const int lane = tid & 63, wvi = tid >> 6;
  const int c = lane & 15, qd = lane >> 4;
  const int lt = wvi * 4 + qd;
  const int t = t0 + lt;
  const int f0 = (c & 3) * 8;
  const unsigned short* xrow = xs + lt * 1024;
  const float aQ = aq[0], aK = aq[1], aV = aq[2];

  for (int p = 0; p < 4; ++p) {
    const int ch = (c >> 2) + (p << 2);
    float acq[8], ack[8], acv[8];
#pragma unroll
    for (int j = 0; j < 8; ++j) {
      acq[j] = sB[ch]; ack[j] = sB[16 + ch]; acv[j] = sB[32 + ch];
    }
    const float* wqp = sW + ch * 32;
    const float* wkp = sW + 512 + ch * 32;
    const float* wvp = sW + 1024 + ch * 32;
    for (int i = 0; i < 32; ++i) {
      BFrag xf;
      xf.v = *(const bf16x8*)(xrow + i * 32 + f0);
      float wqi = wqp[i], wki = wkp[i], wvi2 = wvp[i];
#pragma unroll
      for (int j = 0; j < 8; ++j) {
        float xv = __uint_as_float((unsigned int)xf.s[j] << 16);
        acq[j] += wqi * xv; ack[j] += wki * xv; acv[j] += wvi2 * xv;
      }
    }
    // PReLU + pack + store Q,K (16B coalesced); V via LDS transpose
    unsigned int qw[4], kw[4];
#pragma unroll
    for (int j2 = 0; j2 < 4; ++j2) {
      float q0 = acq[2 * j2], q1 = acq[2 * j2 + 1];
      q0 = q0 > 0.f ? q0 : aQ * q0; q1 = q1 > 0.f ? q1 : aQ * q1;
      qw[j2] = (unsigned int)f2bf(q0) | ((unsigned int)f2bf(q1) << 16);
      float k0 = ack[2 * j2], k1 = ack[2 * j2 + 1];
      k0 = k0 > 0.f ? k0 : aK * k0; k1 = k1 > 0.f ? k1 : aK * k1;
      kw[j2] = (unsigned int)f2bf(k0) | ((unsigned int)f2bf(k1) << 16);
    }
    const int d0 = (p << 7) + (c << 3);
    uintx4 qv, kv;
    qv[0] = qw[0]; qv[1] = qw[1]; qv[2] = qw[2]; qv[3] = qw[3];
    kv[0] = kw[0]; kv[1] = kw[1]; kv[2] = kw[2]; kv[3] = kw[3];
    *(uintx4*)(Q + (size_t)(b * 4000 + t) * 512 + d0) = qv;
    *(uintx4*)(K + (size_t)(b * 4096 + t) * 512 + d0) = kv;
#pragma unroll
    for (int j = 0; j < 8; ++j) {
      float v0 = acv[j];
      v0 = v0 > 0.f ? v0 : aV * v0;
      vsm[(d0 + j) * 18 + lt] = f2bf(v0);
    }
  }
  __syncthreads();
  for (int i = tid; i < 4096; i += 256) {
    int d = i >> 3, u = i & 7;
    unsigned int w2 = *(unsigned int*)&vsm[d * 18 + 2 * u];
    ((unsigned int*)(V + (size_t)(b * 512 + d) * 4096 + t0))[u] = w2;
  }
}

// ---------------- Kernel 2: fused sigmoid-attention + enc ConvBlock ---------
// One wave per 16 tokens. S'[s,t] = K·Q^T via mfma16x16x32; sigmoid in-reg;
// ds_bpermute redistributes C/D frag -> B frag; O'[d,t] += V'·P'.
// Epilogue: enc 1x1 conv + BN + PReLU + residual, fused, writes [B,C,F,T].
__global__ __launch_bounds__(256, 2) void attn_kernel(
    const float* __restrict__ x,
    const float* __restrict__ encW, const float* __restrict__ encb,
    const float* __restrict__ encg, const float* __restrict__ encbe,
    const float* __restrict__ encm, const float* __restrict__ encv,
    const float* __restrict__ enca,
    const unsigned short* __restrict__ Q, const unsigned short* __restrict__ K,
    const unsigned short* __restrict__ V, float* __restrict__ out) {
  const int tid = threadIdx.x;
  const int lane = tid & 63;
  const int wv = (blockIdx.x << 2) + (tid >> 6);
  const int b = wv / 250;
  const int tt = wv - b * 250;
  const int t0 = tt << 4;
  const int c = lane & 15, qd = lane >> 4;

  bf16x8 qf[16];
  {
    const unsigned short* qp = Q + (size_t)(b * 4000 + t0 + c) * 512 + qd * 8;
#pragma unroll
    for (int ks = 0; ks < 16; ++ks) qf[ks] = *(const bf16x8*)(qp + ks * 32);
  }

  floatx4 acc[32];
#pragma unroll
  for (int md = 0; md < 32; ++md) {
    acc[md][0] = 0.f; acc[md][1] = 0.f; acc[md][2] = 0.f; acc[md][3] = 0.f;
  }

  const unsigned short* Kb = K + (size_t)b * 4096 * 512;
  const unsigned short* Vb = V + (size_t)b * 512 * 4096;
  const int srcA = ((((qd << 1) & 3) << 4) | c) << 2;  // byte index for bpermute
  const int srcB = srcA + 64;

  for (int s0 = 0; s0 < 4096; s0 += 32) {
    floatx4 sa0, sa1;
    sa0[0] = sa0[1] = sa0[2] = sa0[3] = 0.f;
    sa1 = sa0;
    const unsigned short* kp0 = Kb + (size_t)(s0 + c) * 512 + qd * 8;
    const unsigned short* kp1 = kp0 + 16 * 512;
#pragma unroll 4
    for (int ks = 0; ks < 16; ++ks) {
      bf16x8 k0 = *(const bf16x8*)(kp0 + ks * 32);
      bf16x8 k1 = *(const bf16x8*)(kp1 + ks * 32);
      sa0 = __builtin_amdgcn_mfma_f32_16x16x32_bf16(k0, qf[ks], sa0, 0, 0, 0);
      sa1 = __builtin_amdgcn_mfma_f32_16x16x32_bf16(k1, qf[ks], sa1, 0, 0, 0);
    }
    // sigmoid -> bf16 pairs
    float p0 = __builtin_amdgcn_rcpf(1.f + __expf(-sa0[0]));
    float p1 = __builtin_amdgcn_rcpf(1.f + __expf(-sa0[1]));
    float p2 = __builtin_amdgcn_rcpf(1.f + __expf(-sa0[2]));
    float p3 = __builtin_amdgcn_rcpf(1.f + __expf(-sa0[3]));
    float p4 = __builtin_amdgcn_rcpf(1.f + __expf(-sa1[0]));
    float p5 = __builtin_amdgcn_rcpf(1.f + __expf(-sa1[1]));
    float p6 = __builtin_amdgcn_rcpf(1.f + __expf(-sa1[2]));
    float p7 = __builtin_amdgcn_rcpf(1.f + __expf(-sa1[3]));
    int w0 = (int)((unsigned int)f2bf(p0) | ((unsigned int)f2bf(p1) << 16));
    int w1 = (int)((unsigned int)f2bf(p2) | ((unsigned int)f2bf(p3) << 16));
    int w2 = (int)((unsigned int)f2bf(p4) | ((unsigned int)f2bf(p5) << 16));
    int w3 = (int)((unsigned int)f2bf(p6) | ((unsigned int)f2bf(p7) << 16));
    // redistribute C/D layout -> B-operand layout (k = quad*8+j over s)
    const bool lo = qd < 2;
    int b0a = __builtin_amdgcn_ds_bpermute(srcA, w0);
    int b0b = __builtin_amdgcn_ds_bpermute(srcA, w2);
    int b1a = __builtin_amdgcn_ds_bpermute(srcA, w1);
    int b1b = __builtin_amdgcn_ds_bpermute(srcA, w3);
    int b2a = __builtin_amdgcn_ds_bpermute(srcB, w0);
    int b2b = __builtin_amdgcn_ds_bpermute(srcB, w2);
    int b3a = __builtin_amdgcn_ds_bpermute(srcB, w1);
    int b3b = __builtin_amdgcn_ds_bpermute(srcB, w3);
    BFrag pf;
    pf.i[0] = lo ? b0a : b0b;
    pf.i[1] = lo ? b1a : b1b;
    pf.i[2] = lo ? b2a : b2b;
    pf.i[3] = lo ? b3a : b3b;

    const unsigned short* vp = Vb + (size_t)c * 4096 + s0 + qd * 8;
#pragma unroll 4
    for (int md = 0; md < 32; ++md) {
      bf16x8 vf = *(const bf16x8*)(vp + (size_t)md * 16 * 4096);
      acc[md] = __builtin_amdgcn_mfma_f32_16x16x32_bf16(vf, pf.v, acc[md], 0, 0, 0);
    }
  }

  // ---- fused enc ConvBlock + residual epilogue ----
  const float ealpha = enca[0];
#pragma unroll 1
  for (int o = 0; o < 32; ++o) {
    float inv = encg[o] * rsqrtf(encv[o] + EPSF);
    float bfo = (encb[o] - encm[o]) * inv + encbe[o];
    float wr[16];
#pragma unroll
    for (int i = 0; i < 16; ++i) wr[i] = encW[o * 16 + i];
#pragma unroll
    for (int hi = 0; hi < 2; ++hi) {
#pragma unroll
      for (int rr = 0; rr < 4; ++rr) {
        float e = 0.f;
#pragma unroll
        for (int i = 0; i < 16; ++i) e += wr[i] * acc[2 * i + hi][rr];
        e = e * inv + bfo;
        e = e > 0.f ? e : ealpha * e;
        int fq = (qd << 2) + rr + (hi << 4);
        size_t idx = ((size_t)((b << 5) + o) * 32 + fq) * 4000 + t0 + c;
        out[idx] = e + x[idx];
      }
    }
  }
}

extern "C" void kernel_launch(void* const* d_in, const int* in_sizes, int n_in,
                              void* d_out, int out_size, void* d_ws,
                              size_t ws_size, hipStream_t stream) {
  const float* x = (const float*)d_in[0];
  unsigned short* Q = (unsigned short*)d_ws;
  unsigned short* K = Q + (size_t)8 * 4000 * 512;
  unsigned short* V = K + (size_t)8 * 4096 * 512;

  dim3 g1(256, 8);
  qkv_kernel<<<g1, 256, 0, stream>>>(
      x, (const float*)d_in[1], (const float*)d_in[2], (const float*)d_in[3],
      (const float*)d_in[4], (const float*)d_in[5], (const float*)d_in[6],
      (const float*)d_in[7], Q, K, V);

  attn_kernel<<<dim3(500), 256, 0, stream>>>(
      x, (const float*)d_in[8], (const float*)d_in[9], (const float*)d_in[10],
      (const float*)d_in[11], (const float*)d_in[12], (const float*)d_in[13],
      (const float*)d_in[14], Q, K, V, (float*)d_out);
}

// Round 2
// 788.185 us; speedup vs baseline: 5.7874x; 5.7874x over previous
//
#include <hip/hip_runtime.h>

typedef __attribute__((ext_vector_type(8))) short bf16x8;
typedef __attribute__((ext_vector_type(4))) float floatx4;
typedef __attribute__((ext_vector_type(4))) unsigned int uintx4;

#define EPSF 1e-5f
#define RS512 0.04419417382415922f /* 1/sqrt(512) */

__device__ __forceinline__ unsigned short f2bf(float f) {
  unsigned int u = __float_as_uint(f);
  u += 0x7fffu + ((u >> 16) & 1u);
  return (unsigned short)(u >> 16);
}

union BFrag { bf16x8 v; int i[4]; unsigned short s[8]; };

// ---------------- Kernel 1: fused qkv conv + BN + PReLU, bf16 emit ----------
// Q: [8][4000][512] token-major; K: [8][4000][512] token-major (pre-scaled by
// 1/sqrt(512)); V: tiled [8][125][512][32] (s-tile-major, d rows of 32 tokens)
__global__ __launch_bounds__(256) void qkv_kernel(
    const float* __restrict__ x,
    const float* __restrict__ Wq, const float* __restrict__ bq,
    const float* __restrict__ gq, const float* __restrict__ beq,
    const float* __restrict__ mq, const float* __restrict__ vq,
    const float* __restrict__ aq,
    unsigned short* __restrict__ Q, unsigned short* __restrict__ K,
    unsigned short* __restrict__ V) {
  const int b = blockIdx.y;
  const int t0 = blockIdx.x << 4;  // 250 blocks: t0 in [0,4000)
  const int tid = threadIdx.x;

  __shared__ unsigned short xs[16 * 1024];  // [lt][i*32+f] bf16  (32 KB)
  __shared__ float sW[1536];                // folded qkv weights
  __shared__ float sB[48];                  // folded qkv biases
  __shared__ unsigned short vsm[512 * 18];  // V transpose staging (18 KB)

  // fold BN into conv weights/bias (K additionally scaled by 1/sqrt(512))
  for (int idx = tid; idx < 1536; idx += 256) {
    int n = idx >> 9, ch = (idx >> 5) & 15;
    float inv = gq[n * 16 + ch] * rsqrtf(vq[n * 16 + ch] + EPSF);
    if (n == 1) inv *= RS512;
    sW[idx] = Wq[idx] * inv;
  }
  if (tid < 48) {
    int n = tid >> 4;
    float inv = gq[tid] * rsqrtf(vq[tid] + EPSF);
    float bb = (bq[tid] - mq[tid]) * inv + beq[tid];
    if (n == 1) bb *= RS512;
    sB[tid] = bb;
  }
  {  // stage x[b,:,:,t0..t0+15] into LDS, t-major, bf16
    int lt = tid & 15, rg = tid >> 4;
    const float* xb = x + (size_t)b * 1024 * 4000 + t0 + lt;
    for (int rr = rg; rr < 1024; rr += 16)
      xs[lt * 1024 + rr] = f2bf(xb[(size_t)rr * 4000]);
  }
  __syncthreads();

  const int lane = tid & 63, wvi = tid >> 6;
  const int c = lane & 15, qd = lane >> 4;
  const int lt = wvi * 4 + qd;
  const int t = t0 + lt;
  const int f0 = (c & 3) * 8;
  const unsigned short* xrow = xs + lt * 1024;
  const float aQ = aq[0], aK = aq[1], aV = aq[2];

  for (int p = 0; p < 4; ++p) {
    const int ch = (c >> 2) + (p << 2);
    float acq[8], ack[8], acv[8];
#pragma unroll
    for (int j = 0; j < 8; ++j) {
      acq[j] = sB[ch]; ack[j] = sB[16 + ch]; acv[j] = sB[32 + ch];
    }
    const float* wqp = sW + ch * 32;
    const float* wkp = sW + 512 + ch * 32;
    const float* wvp = sW + 1024 + ch * 32;
    for (int i = 0; i < 32; ++i) {
      BFrag xf;
      xf.v = *(const bf16x8*)(xrow + i * 32 + f0);
      float wqi = wqp[i], wki = wkp[i], wvi2 = wvp[i];
#pragma unroll
      for (int j = 0; j < 8; ++j) {
        float xv = __uint_as_float((unsigned int)xf.s[j] << 16);
        acq[j] += wqi * xv; ack[j] += wki * xv; acv[j] += wvi2 * xv;
      }
    }
    // PReLU + pack + store Q,K (16B coalesced); V via LDS transpose
    unsigned int qw[4], kw[4];
#pragma unroll
    for (int j2 = 0; j2 < 4; ++j2) {
      float q0 = acq[2 * j2], q1 = acq[2 * j2 + 1];
      q0 = q0 > 0.f ? q0 : aQ * q0; q1 = q1 > 0.f ? q1 : aQ * q1;
      qw[j2] = (unsigned int)f2bf(q0) | ((unsigned int)f2bf(q1) << 16);
      float k0 = ack[2 * j2], k1 = ack[2 * j2 + 1];
      k0 = k0 > 0.f ? k0 : aK * k0; k1 = k1 > 0.f ? k1 : aK * k1;
      kw[j2] = (unsigned int)f2bf(k0) | ((unsigned int)f2bf(k1) << 16);
    }
    const int d0 = (p << 7) + (c << 3);
    uintx4 qv, kv;
    qv[0] = qw[0]; qv[1] = qw[1]; qv[2] = qw[2]; qv[3] = qw[3];
    kv[0] = kw[0]; kv[1] = kw[1]; kv[2] = kw[2]; kv[3] = kw[3];
    *(uintx4*)(Q + (size_t)(b * 4000 + t) * 512 + d0) = qv;
    *(uintx4*)(K + (size_t)(b * 4000 + t) * 512 + d0) = kv;
#pragma unroll
    for (int j = 0; j < 8; ++j) {
      float v0 = acv[j];
      v0 = v0 > 0.f ? v0 : aV * v0;
      vsm[(d0 + j) * 18 + lt] = f2bf(v0);
    }
  }
  __syncthreads();
  {
    const int st = t0 >> 5;
    const int toff = t0 & 16;
    unsigned short* vt = V + ((size_t)(b * 125 + st) * 512) * 32 + toff;
    for (int i = tid; i < 4096; i += 256) {
      int d = i >> 3, u = i & 7;
      unsigned int w2 = *(unsigned int*)&vsm[d * 18 + 2 * u];
      ((unsigned int*)(vt + d * 32))[u] = w2;
    }
  }
}

// ---------------- Kernel 2: LDS-staged sigmoid-attention + enc ConvBlock ----
// 512 threads = 8 waves, each wave owns 16 q-tokens (block = 128 tokens).
// Sweep 125 s-tiles of 32; K/V tiles staged in LDS (padded, conflict-free),
// software-pipelined global prefetch. Epilogue fuses enc conv+BN+PReLU+res.
__global__ __launch_bounds__(512, 2) void attn_kernel(
    const float* __restrict__ x,
    const float* __restrict__ encW, const float* __restrict__ encb,
    const float* __restrict__ encg, const float* __restrict__ encbe,
    const float* __restrict__ encm, const float* __restrict__ encv,
    const float* __restrict__ enca,
    const unsigned short* __restrict__ Q, const unsigned short* __restrict__ K,
    const unsigned short* __restrict__ V, float* __restrict__ out) {
  const int tid = threadIdx.x;
  const int lane = tid & 63;
  const int w = tid >> 6;
  const int b = blockIdx.x >> 5;           // 8 b * 32 blocks
  const int bt0 = (blockIdx.x & 31) << 7;  // 0..3968
  const int t0 = bt0 + (w << 4);
  const bool active = t0 < 4000;
  const int c = lane & 15, qd = lane >> 4;

  __shared__ unsigned short Ks[32 * 520];   // row pad +8 shorts
  __shared__ unsigned short Vs[512 * 40];   // row pad +8 shorts

  // Q fragments for this wave's 16 tokens (B operand of S-mfma)
  bf16x8 qf[16];
  {
    const int tq = active ? t0 : 0;
    const unsigned short* qp = Q + (size_t)(b * 4000 + tq + c) * 512 + qd * 8;
#pragma unroll
    for (int ks = 0; ks < 16; ++ks) qf[ks] = *(const bf16x8*)(qp + ks * 32);
  }

  floatx4 acc[32];
#pragma unroll
  for (int md = 0; md < 32; ++md) {
    acc[md][0] = 0.f; acc[md][1] = 0.f; acc[md][2] = 0.f; acc[md][3] = 0.f;
  }

  const unsigned short* Kb = K + (size_t)b * 4000 * 512;
  const unsigned short* Vb = V + (size_t)b * 125 * 16384;
  const int srcA = ((((qd << 1) & 3) << 4) | c) << 2;  // bpermute byte index
  const int srcB = srcA + 64;

  // prefetch tile 0 into registers
  uintx4 kv[4], vv[4];
#pragma unroll
  for (int j = 0; j < 4; ++j) {
    int id = tid + (j << 9);
    kv[j] = *(const uintx4*)(Kb + (size_t)id * 8);
    vv[j] = *(const uintx4*)(Vb + (size_t)id * 8);
  }

#pragma unroll 1
  for (int it = 0; it < 125; ++it) {
    __syncthreads();  // all waves done reading previous LDS tile
#pragma unroll
    for (int j = 0; j < 4; ++j) {
      int id = tid + (j << 9);
      int kr = id >> 6, kc = id & 63;
      *(uintx4*)(Ks + kr * 520 + kc * 8) = kv[j];
      int vd = id >> 2, vc = id & 3;
      *(uintx4*)(Vs + vd * 40 + vc * 8) = vv[j];
    }
    __syncthreads();
    {  // prefetch next tile (re-loads current on final iter; harmless)
      const int nit = (it + 1 < 125) ? it + 1 : it;
      const unsigned short* kg = Kb + (size_t)nit * 32 * 512;
      const unsigned short* vg = Vb + (size_t)nit * 16384;
#pragma unroll
      for (int j = 0; j < 4; ++j) {
        int id = tid + (j << 9);
        kv[j] = *(const uintx4*)(kg + (size_t)id * 8);
        vv[j] = *(const uintx4*)(vg + (size_t)id * 8);
      }
    }
    if (active) {
      floatx4 sa0, sa1;
      sa0[0] = sa0[1] = sa0[2] = sa0[3] = 0.f;
      sa1 = sa0;
      const unsigned short* kp = Ks + c * 520 + qd * 8;
#pragma unroll
      for (int ks = 0; ks < 16; ++ks) {
        bf16x8 k0 = *(const bf16x8*)(kp + ks * 32);
        bf16x8 k1 = *(const bf16x8*)(kp + 16 * 520 + ks * 32);
        sa0 = __builtin_amdgcn_mfma_f32_16x16x32_bf16(k0, qf[ks], sa0, 0, 0, 0);
        sa1 = __builtin_amdgcn_mfma_f32_16x16x32_bf16(k1, qf[ks], sa1, 0, 0, 0);
      }
      // sigmoid -> packed bf16
      float p0 = __builtin_amdgcn_rcpf(1.f + __expf(-sa0[0]));
      float p1 = __builtin_amdgcn_rcpf(1.f + __expf(-sa0[1]));
      float p2 = __builtin_amdgcn_rcpf(1.f + __expf(-sa0[2]));
      float p3 = __builtin_amdgcn_rcpf(1.f + __expf(-sa0[3]));
      float p4 = __builtin_amdgcn_rcpf(1.f + __expf(-sa1[0]));
      float p5 = __builtin_amdgcn_rcpf(1.f + __expf(-sa1[1]));
      float p6 = __builtin_amdgcn_rcpf(1.f + __expf(-sa1[2]));
      float p7 = __builtin_amdgcn_rcpf(1.f + __expf(-sa1[3]));
      int w0 = (int)((unsigned int)f2bf(p0) | ((unsigned int)f2bf(p1) << 16));
      int w1 = (int)((unsigned int)f2bf(p2) | ((unsigned int)f2bf(p3) << 16));
      int w2 = (int)((unsigned int)f2bf(p4) | ((unsigned int)f2bf(p5) << 16));
      int w3 = (int)((unsigned int)f2bf(p6) | ((unsigned int)f2bf(p7) << 16));
      // redistribute C/D layout -> B-operand layout
      const bool lo = qd < 2;
      int b0a = __builtin_amdgcn_ds_bpermute(srcA, w0);
      int b0b = __builtin_amdgcn_ds_bpermute(srcA, w2);
      int b1a = __builtin_amdgcn_ds_bpermute(srcA, w1);
      int b1b = __builtin_amdgcn_ds_bpermute(srcA, w3);
      int b2a = __builtin_amdgcn_ds_bpermute(srcB, w0);
      int b2b = __builtin_amdgcn_ds_bpermute(srcB, w2);
      int b3a = __builtin_amdgcn_ds_bpermute(srcB, w1);
      int b3b = __builtin_amdgcn_ds_bpermute(srcB, w3);
      BFrag pf;
      pf.i[0] = lo ? b0a : b0b;
      pf.i[1] = lo ? b1a : b1b;
      pf.i[2] = lo ? b2a : b2b;
      pf.i[3] = lo ? b3a : b3b;

      const unsigned short* vp = Vs + c * 40 + qd * 8;
#pragma unroll
      for (int md = 0; md < 32; ++md) {
        bf16x8 vf = *(const bf16x8*)(vp + md * 16 * 40);
        acc[md] = __builtin_amdgcn_mfma_f32_16x16x32_bf16(vf, pf.v, acc[md], 0, 0, 0);
      }
    }
  }

  // ---- fused enc ConvBlock + residual epilogue ----
  if (active) {
    const float ealpha = enca[0];
#pragma unroll 1
    for (int o = 0; o < 32; ++o) {
      float inv = encg[o] * rsqrtf(encv[o] + EPSF);
      float bfo = (encb[o] - encm[o]) * inv + encbe[o];
      float wr[16];
#pragma unroll
      for (int i = 0; i < 16; ++i) wr[i] = encW[o * 16 + i];
#pragma unroll
      for (int hi = 0; hi < 2; ++hi) {
#pragma unroll
        for (int rr = 0; rr < 4; ++rr) {
          float e = 0.f;
#pragma unroll
          for (int i = 0; i < 16; ++i) e += wr[i] * acc[2 * i + hi][rr];
          e = e * inv + bfo;
          e = e > 0.f ? e : ealpha * e;
          int fq = (qd << 2) + rr + (hi << 4);
          size_t idx = ((size_t)((b << 5) + o) * 32 + fq) * 4000 + t0 + c;
          out[idx] = e + x[idx];
        }
      }
    }
  }
}

extern "C" void kernel_launch(void* const* d_in, const int* in_sizes, int n_in,
                              void* d_out, int out_size, void* d_ws,
                              size_t ws_size, hipStream_t stream) {
  const float* x = (const float*)d_in[0];
  unsigned short* Q = (unsigned short*)d_ws;
  unsigned short* K = Q + (size_t)8 * 4000 * 512;
  unsigned short* V = K + (size_t)8 * 4000 * 512;

  dim3 g1(250, 8);
  qkv_kernel<<<g1, 256, 0, stream>>>(
      x, (const float*)d_in[1], (const float*)d_in[2], (const float*)d_in[3],
      (const float*)d_in[4], (const float*)d_in[5], (const float*)d_in[6],
      (const float*)d_in[7], Q, K, V);

  attn_kernel<<<dim3(256), 512, 0, stream>>>(
      x, (const float*)d_in[8], (const float*)d_in[9], (const float*)d_in[10],
      (const float*)d_in[11], (const float*)d_in[12], (const float*)d_in[13],
      (const float*)d_in[14], Q, K, V, (float*)d_out);
}